// Round 4
// baseline (428.613 us; speedup 1.0000x reference)
//
#include <hip/hip_runtime.h>
#include <stdint.h>

// Problem constants (from reference): B=8, L=4096, D=1024, S=255
constexpr int kB = 8;
constexpr int kL = 4096;
constexpr int kD = 1024;
constexpr int kS = 255;
constexpr int kM = kB * kL;   // 32768 rows of A / out
constexpr int kK = 2 * kD;    // 2048 reduction dim
constexpr int kN = kD;        // 1024 output features

typedef __bf16 bf16x8 __attribute__((ext_vector_type(8)));
typedef float  f32x4  __attribute__((ext_vector_type(4)));

// ---- workspace layout (bytes): W in bf16 + 4 KB zero page only ----
constexpr size_t WS_W    = 0;                         // [1024][2048] bf16 = 4 MiB
constexpr size_t WS_ZP   = (size_t)kN * kK * 2;       // 4,194,304
constexpr size_t WS_NEED = WS_ZP + 4096;              // zero page 4 KiB (fp32 zeros)

// fp32 pair -> packed bf16x2 (a in low 16), round-half-up (validated R0-R3)
__device__ __forceinline__ uint32_t pk_bf16x2(float a, float b) {
    uint32_t ua = __float_as_uint(a) + 0x8000u;
    uint32_t ub = __float_as_uint(b) + 0x8000u;
    return __builtin_amdgcn_perm(ub, ua, 0x07060302u);
}

// async global->LDS 16B per lane: dest = wave-uniform base + lane*16
__device__ __forceinline__ void async16(const void* g, void* l) {
    __builtin_amdgcn_global_load_lds(
        (const __attribute__((address_space(1))) uint32_t*)g,
        (__attribute__((address_space(3))) uint32_t*)l, 16, 0, 0);
}

#define WAITVM(n)  asm volatile("s_waitcnt vmcnt(" #n ")" ::: "memory")
#define WAITLGKM0  asm volatile("s_waitcnt lgkmcnt(0)" ::: "memory")

__device__ __forceinline__ void blockbar() {
    __builtin_amdgcn_sched_barrier(0);
    __builtin_amdgcn_s_barrier();
    __builtin_amdgcn_sched_barrier(0);
}

// ============ tiny prepass: W fp32 -> bf16 (4 MiB) + 4 KiB zero page ========
__global__ __launch_bounds__(256)
void cvt_w(const float4* __restrict__ W, uint4* __restrict__ WB,
           uint32_t* __restrict__ zp)
{
    if (blockIdx.x == 0) {
        for (int t = threadIdx.x; t < 1024; t += 256) zp[t] = 0u;  // 4 KB zeros
    }
    size_t i = (size_t)blockIdx.x * 256 + threadIdx.x;   // 262144 items exactly
    float4 a  = W[2 * i];
    float4 b2 = W[2 * i + 1];
    uint4 o;
    o.x = pk_bf16x2(a.x,  a.y);
    o.y = pk_bf16x2(a.z,  a.w);
    o.z = pk_bf16x2(b2.x, b2.y);
    o.w = pk_bf16x2(b2.z, b2.w);
    WB[i] = o;
}

// ===================== GEMM v4: fused fp32 A-staging, reg double-buffer =====
// C[m,n] = relu( sum_k A[m,k]*W[n,k] + bias[n] ),  A = [words | sent-gather]
// 256x256 tile, BK=32, 8 waves (2Mx4N, 128x64/wave), 4 LDS buffers (128 KiB).
// v4 fix over v3: A-stage register DOUBLE-buffer. kstep t phase A loads tile
// t+4 into regset R[t&1]; phase B writes regset R[(t+1)&1] (tile t+3, loaded
// one kstep earlier) to LDS. Load->use distance ~1.5 ksteps >> HBM latency,
// removing v3's per-kstep vmcnt drain on the A loads (the 154->236 regression).
// vmcnt ledger (per kstep: 4 A-loads phase A, 2 B-DMAs phase B): at kstep-t
// mid, ops younger than B-DMA(t+1) = loads(t+3)4 + DMA(t+2)2 + loads(t+4)4
// = 10 -> steady-state WAITVM(10); tail (t>=60, issue guards kick in) -> 0.
// lgkmcnt(0)+sched_barrier before each s_barrier (v2.1 discipline).
__global__ __launch_bounds__(512, 2)
void wsib_gemm_v4(const float* __restrict__ words,   // [32768][1024] f32
                  const float* __restrict__ sents,   // [8*255][1024] f32
                  const uint8_t* __restrict__ WB,    // [1024][2048]  bf16
                  const float*   __restrict__ bias,
                  const int*     __restrict__ smap,
                  const float*   __restrict__ zpF,   // 4 KB zeros
                  float* __restrict__ out)
{
    __shared__ uint8_t lds[4][2][16384];   // [buf][A=0/B=1][256 rows][64 B]

    const int tid  = threadIdx.x;
    const int w    = tid >> 6;           // wave 0..7
    const int lane = tid & 63;

    // XCD-aware block swizzle (bijective, 512 = 8*64): each XCD covers 16 mT
    // x all 4 nT -> A-panel reuse stays within one XCD's L2.
    const int lin = blockIdx.y * gridDim.x + blockIdx.x;   // 0..511
    const int swz = (lin & 7) * 64 + (lin >> 3);
    const int nT = swz & 3;              // 0..3
    const int mT = swz >> 2;             // 0..127

    const int wm = (w >> 2) * 128;
    const int wn = (w & 3) * 64;
    const int fr = lane & 15, quad = lane >> 4;

    float bv[4];
    #pragma unroll
    for (int ni = 0; ni < 4; ++ni) bv[ni] = bias[nT * 256 + wn + ni * 16 + fr];

    // ---- A staging (reg->LDS): seg s covers LDS row s*128 + (tid>>2), chunk tid&3
    const int c = tid & 3;                       // 8-float chunk within K-step
    const int gR0 = mT * 256 + (tid >> 2);       // seg 0 global row
    const int gR1 = gR0 + 128;                   // seg 1
    const float* pW0 = words + (size_t)gR0 * kD + c * 8;
    const float* pW1 = words + (size_t)gR1 * kD + c * 8;
    const int bIdx = gR0 >> 12;                  // tile never crosses batch
    const int s0 = smap[gR0], s1 = smap[gR1];
    const float* pS0 = (s0 >= 0) ? sents + (size_t)(bIdx * kS + s0) * kD + c * 8
                                 : zpF + c * 8;
    const float* pS1 = (s1 >= 0) ? sents + (size_t)(bIdx * kS + s1) * kD + c * 8
                                 : zpF + c * 8;

    // ---- B staging (DMA): rows w*32+(lane>>2) and +16, chunk lane&3, linear LDS
    const int rB0 = w * 32 + (lane >> 2);
    const uint8_t* pB0 = WB + (size_t)(nT * 256 + rB0) * (kK * 2) + (lane & 3) * 16;
    const uint8_t* pB1 = pB0 + (size_t)16 * (kK * 2);

    // ---- fragment read offsets (linear layout — bank-minimal for b128) ----
    const int offA = (wm + fr) * 64 + quad * 16;   // + mi*1024
    const int offB = (wn + fr) * 64 + quad * 16;   // + ni*1024

    f32x4 acc[8][4];
    #pragma unroll
    for (int i = 0; i < 8; ++i)
        #pragma unroll
        for (int j = 0; j < 4; ++j) acc[i][j] = (f32x4){0.f, 0.f, 0.f, 0.f};

    auto stageA_load = [&](int t, float4 (&st)[4]) {
        const float* p0 = (t < 32) ? pW0 + t * 32 : pS0 + (t - 32) * 32;
        const float* p1 = (t < 32) ? pW1 + t * 32 : pS1 + (t - 32) * 32;
        st[0] = ((const float4*)p0)[0];
        st[1] = ((const float4*)p0)[1];
        st[2] = ((const float4*)p1)[0];
        st[3] = ((const float4*)p1)[1];
    };
    auto stageA_write = [&](uint8_t* bufA, const float4 (&st)[4]) {
        uint4 o0, o1;
        o0.x = pk_bf16x2(st[0].x, st[0].y);  o0.y = pk_bf16x2(st[0].z, st[0].w);
        o0.z = pk_bf16x2(st[1].x, st[1].y);  o0.w = pk_bf16x2(st[1].z, st[1].w);
        o1.x = pk_bf16x2(st[2].x, st[2].y);  o1.y = pk_bf16x2(st[2].z, st[2].w);
        o1.z = pk_bf16x2(st[3].x, st[3].y);  o1.w = pk_bf16x2(st[3].z, st[3].w);
        *(uint4*)(bufA + tid * 16)        = o0;   // seg 0: rows 0..127
        *(uint4*)(bufA + 8192 + tid * 16) = o1;   // seg 1: rows 128..255
    };
    auto stageB_dma = [&](uint8_t* bufB, int t) {
        async16(pB0 + t * 64, bufB + w * 2048);
        async16(pB1 + t * 64, bufB + w * 2048 + 1024);
    };

    float4 stR0[4], stR1[4];   // A-stage register double-buffer

    // ---- prologue: stage tiles 0,1,2 into LDS; prime R1 = A-loads(3) ----
    {
        float4 st[4];
        #pragma unroll
        for (int t = 0; t < 3; ++t) {
            stageA_load(t, st);
            stageA_write((uint8_t*)lds[t][0], st);
            stageB_dma((uint8_t*)lds[t][1], t);
        }
        stageA_load(3, stR1);
    }
    WAITLGKM0;
    WAITVM(8);      // B-DMA(0) retired; DMA(1,2) + loads(3) stay in flight
    blockbar();

    bf16x8 af[4], bfA[4], bfB[4];
    #pragma unroll
    for (int mi = 0; mi < 4; ++mi)
        af[mi] = *(const bf16x8*)((uint8_t*)lds[0][0] + offA + mi * 1024);
    #pragma unroll
    for (int ni = 0; ni < 4; ++ni)
        bfA[ni] = *(const bf16x8*)((uint8_t*)lds[0][1] + offB + ni * 1024);

    // ---- main loop: 64 K-steps, 2 per iteration (bf + regset ping-pong) ----
    auto kstep = [&](int t, bf16x8 (&bfc)[4], bf16x8 (&bfn)[4],
                     float4 (&stLoad)[4], float4 (&stWrite)[4]) {
        uint8_t* bufT  = (uint8_t*)lds[t & 3][0];        // ag source
        uint8_t* bufNA = (uint8_t*)lds[(t + 1) & 3][0];  // next A frags
        uint8_t* bufNB = (uint8_t*)lds[(t + 1) & 3][1];  // next B frags
        uint8_t* bufSA = (uint8_t*)lds[(t + 3) & 3][0];  // staging dest
        uint8_t* bufSB = (uint8_t*)lds[(t + 3) & 3][1];

        // ---- phase A: issue A-loads(t+4) into stLoad, read ag(t), MFMA-A ----
        if (t + 4 < 64) stageA_load(t + 4, stLoad);
        bf16x8 ag[4];
        #pragma unroll
        for (int mi = 0; mi < 4; ++mi)
            ag[mi] = *(const bf16x8*)(bufT + offA + (mi + 4) * 1024);
        __builtin_amdgcn_s_setprio(1);
        #pragma unroll
        for (int mi = 0; mi < 4; ++mi)
            #pragma unroll
            for (int ni = 0; ni < 4; ++ni)
                acc[mi][ni] = __builtin_amdgcn_mfma_f32_16x16x32_bf16(
                    af[mi], bfc[ni], acc[mi][ni], 0, 0, 0);
        __builtin_amdgcn_s_setprio(0);

        // ---- mid: drain own DS ops; B-DMA(t+1) retired; barrier ----
        WAITLGKM0;
        if (t < 60) { WAITVM(10); } else { WAITVM(0); }
        blockbar();

        // ---- phase B: next frags, stage tile t+3 (B-DMA + A reg->LDS), MFMA-B
        if (t + 1 < 64) {
            #pragma unroll
            for (int ni = 0; ni < 4; ++ni)
                bfn[ni] = *(const bf16x8*)(bufNB + offB + ni * 1024);
            #pragma unroll
            for (int mi = 0; mi < 4; ++mi)
                af[mi] = *(const bf16x8*)(bufNA + offA + mi * 1024);
        }
        if (t + 3 < 64) {
            stageB_dma(bufSB, t + 3);
            stageA_write(bufSA, stWrite);   // regset loaded at kstep t-1
        }
        __builtin_amdgcn_s_setprio(1);
        #pragma unroll
        for (int mi = 0; mi < 4; ++mi)
            #pragma unroll
            for (int ni = 0; ni < 4; ++ni)
                acc[mi + 4][ni] = __builtin_amdgcn_mfma_f32_16x16x32_bf16(
                    ag[mi], bfc[ni], acc[mi + 4][ni], 0, 0, 0);
        __builtin_amdgcn_s_setprio(0);
    };

    #pragma unroll 1
    for (int t2 = 0; t2 < 32; ++t2) {
        kstep(2 * t2,     bfA, bfB, stR0, stR1);   // even: load R0, write R1
        kstep(2 * t2 + 1, bfB, bfA, stR1, stR0);   // odd:  load R1, write R0
    }

    // ---- epilogue: bias + relu, fp32 store ----
    // C/D layout (verified): col = lane&15, row = quad*4 + r
    const int rowBase = mT * 256 + wm + quad * 4;
    const int colBase = nT * 256 + wn + fr;
    #pragma unroll
    for (int mi = 0; mi < 8; ++mi) {
        #pragma unroll
        for (int ni = 0; ni < 4; ++ni) {
            const int col = colBase + ni * 16;
            #pragma unroll
            for (int r = 0; r < 4; ++r) {
                const int row = rowBase + mi * 16 + r;
                out[(size_t)row * kN + col] = fmaxf(acc[mi][ni][r] + bv[ni], 0.f);
            }
        }
    }
}

// ===================== fallback (R2 kernel, no-workspace path) ==============
#define TILE_M 128
#define TILE_N 128
#define TILE_K 32
#define LDS_STRIDE 20
__global__ __launch_bounds__(256)
void wsib_gemm_fb(const float* __restrict__ words, const float* __restrict__ sents,
                  const float* __restrict__ W, const float* __restrict__ bias,
                  const int* __restrict__ smap, float* __restrict__ out)
{
    __shared__ uint32_t Asm[TILE_M * LDS_STRIDE];
    __shared__ uint32_t Bsm[TILE_N * LDS_STRIDE];
    const int tid = threadIdx.x, nT = blockIdx.x, mT = blockIdx.y;
    const int sRow = tid >> 1, half = tid & 1;
    const int mRow = mT * TILE_M + sRow, bIdx = mRow >> 12;
    const float* wsrc = words + (size_t)mRow * kD + half * 16;
    const int sidx = smap[mRow];
    const float* ssrc = (sidx >= 0) ? sents + ((size_t)bIdx * kS + sidx) * kD + half * 16 : nullptr;
    const float* bsrc = W + (size_t)(nT * TILE_N + sRow) * kK + half * 16;
    uint32_t* adst = &Asm[sRow * LDS_STRIDE + half * 8];
    uint32_t* bdst = &Bsm[sRow * LDS_STRIDE + half * 8];
    const int lane = tid & 63, wv = tid >> 6;
    const int wm = (wv & 1) * 64, wn = (wv >> 1) * 64;
    const int fr = lane & 15, quad = lane >> 4;
    f32x4 acc[4][4];
    #pragma unroll
    for (int i = 0; i < 4; ++i)
        #pragma unroll
        for (int j = 0; j < 4; ++j) acc[i][j] = (f32x4){0.f, 0.f, 0.f, 0.f};
    float4 ra[4], rb[4];
    {
        const float4* pa = (const float4*)wsrc; const float4* pb = (const float4*)bsrc;
        #pragma unroll
        for (int i = 0; i < 4; ++i) { ra[i] = pa[i]; rb[i] = pb[i]; }
    }
    for (int k0 = 0; k0 < kK; k0 += TILE_K) {
        uint32_t pa[8], pb[8];
        #pragma unroll
        for (int i = 0; i < 4; ++i) {
            pa[2*i] = pk_bf16x2(ra[i].x, ra[i].y); pa[2*i+1] = pk_bf16x2(ra[i].z, ra[i].w);
            pb[2*i] = pk_bf16x2(rb[i].x, rb[i].y); pb[2*i+1] = pk_bf16x2(rb[i].z, rb[i].w);
        }
        __syncthreads();
        ((uint4*)adst)[0] = make_uint4(pa[0], pa[1], pa[2], pa[3]);
        ((uint4*)adst)[1] = make_uint4(pa[4], pa[5], pa[6], pa[7]);
        ((uint4*)bdst)[0] = make_uint4(pb[0], pb[1], pb[2], pb[3]);
        ((uint4*)bdst)[1] = make_uint4(pb[4], pb[5], pb[6], pb[7]);
        __syncthreads();
        const int k1 = k0 + TILE_K;
        if (k1 < kK) {
            const float* asrc = (k1 < kD) ? (wsrc + k1) : (ssrc ? (ssrc + (k1 - kD)) : nullptr);
            if (asrc) { const float4* p = (const float4*)asrc;
                #pragma unroll
                for (int i = 0; i < 4; ++i) ra[i] = p[i];
            } else {
                #pragma unroll
                for (int i = 0; i < 4; ++i) ra[i] = make_float4(0.f, 0.f, 0.f, 0.f);
            }
            const float4* p = (const float4*)(bsrc + k1);
            #pragma unroll
            for (int i = 0; i < 4; ++i) rb[i] = p[i];
        }
        bf16x8 af[4], bfv[4];
        #pragma unroll
        for (int mi = 0; mi < 4; ++mi)
            af[mi] = *(const bf16x8*)&Asm[(wm + mi * 16 + fr) * LDS_STRIDE + quad * 4];
        #pragma unroll
        for (int ni = 0; ni < 4; ++ni)
            bfv[ni] = *(const bf16x8*)&Bsm[(wn + ni * 16 + fr) * LDS_STRIDE + quad * 4];
        #pragma unroll
        for (int mi = 0; mi < 4; ++mi)
            #pragma unroll
            for (int ni = 0; ni < 4; ++ni)
                acc[mi][ni] = __builtin_amdgcn_mfma_f32_16x16x32_bf16(af[mi], bfv[ni], acc[mi][ni], 0, 0, 0);
    }
    const int rowBase = mT * TILE_M + wm, colBase = nT * TILE_N + wn;
    float bv[4];
    #pragma unroll
    for (int ni = 0; ni < 4; ++ni) bv[ni] = bias[colBase + ni * 16 + fr];
    #pragma unroll
    for (int mi = 0; mi < 4; ++mi)
        #pragma unroll
        for (int ni = 0; ni < 4; ++ni) {
            const int col = colBase + ni * 16 + fr;
            #pragma unroll
            for (int r = 0; r < 4; ++r) {
                const int row = rowBase + mi * 16 + quad * 4 + r;
                out[(size_t)row * kN + col] = fmaxf(acc[mi][ni][r] + bv[ni], 0.f);
            }
        }
}

extern "C" void kernel_launch(void* const* d_in, const int* in_sizes, int n_in,
                              void* d_out, int out_size, void* d_ws, size_t ws_size,
                              hipStream_t stream) {
    const float* words = (const float*)d_in[0];   // [8, 4096, 1024] f32
    const float* sents = (const float*)d_in[1];   // [8, 255, 1024]  f32
    const float* W     = (const float*)d_in[2];   // [1024, 2048]    f32
    const float* bias  = (const float*)d_in[3];   // [1024]          f32
    const int*   smap  = (const int*)d_in[4];     // [8, 4096]       i32
    float* out = (float*)d_out;                   // [8, 4096, 1024] f32

    if (ws_size >= WS_NEED) {
        uint8_t* ws = (uint8_t*)d_ws;
        uint4* WBv    = (uint4*)(ws + WS_W);
        uint32_t* zp  = (uint32_t*)(ws + WS_ZP);
        cvt_w<<<1024, 256, 0, stream>>>((const float4*)W, WBv, zp);
        dim3 grid(kN / 256, kM / 256);            // (4, 128)
        wsib_gemm_v4<<<grid, 512, 0, stream>>>(
            words, sents, (const uint8_t*)WBv, bias, smap,
            (const float*)(ws + WS_ZP), out);
    } else {
        dim3 grid(kN / TILE_N, kM / TILE_M);
        wsib_gemm_fb<<<grid, 256, 0, stream>>>(words, sents, W, bias, smap, out);
    }
}

// Round 5
// 365.388 us; speedup vs baseline: 1.1730x; 1.1730x over previous
//
#include <hip/hip_runtime.h>
#include <stdint.h>

// Problem constants (from reference): B=8, L=4096, D=1024, S=255
constexpr int kB = 8;
constexpr int kL = 4096;
constexpr int kD = 1024;
constexpr int kS = 255;
constexpr int kM = kB * kL;   // 32768 rows of A / out
constexpr int kK = 2 * kD;    // 2048 reduction dim
constexpr int kN = kD;        // 1024 output features

typedef __bf16 bf16x8 __attribute__((ext_vector_type(8)));
typedef float  f32x4  __attribute__((ext_vector_type(4)));

// ---- workspace layout (bytes): full bf16 mirror (R2 layout) ----
constexpr size_t WS_WORDS = 0;                                   // 67,108,864 B bf16
constexpr size_t WS_SENTS = WS_WORDS + (size_t)kM * kD * 2;
constexpr size_t WS_W     = WS_SENTS + (size_t)kB * kS * kD * 2; // +4,177,920
constexpr size_t WS_ZP    = WS_W + (size_t)kN * kK * 2;          // +4,194,304
constexpr size_t WS_NEED  = WS_ZP + 3072;                        // zero page 3 KiB

// fp32 pair -> packed bf16x2, round-half-up (validated R0-R4)
__device__ __forceinline__ uint32_t pk_bf16x2(float a, float b) {
    uint32_t ua = __float_as_uint(a) + 0x8000u;
    uint32_t ub = __float_as_uint(b) + 0x8000u;
    return __builtin_amdgcn_perm(ub, ua, 0x07060302u);
}

// async global->LDS 16B per lane: dest = wave-uniform base + lane*16
__device__ __forceinline__ void async16(const void* g, void* l) {
    __builtin_amdgcn_global_load_lds(
        (const __attribute__((address_space(1))) uint32_t*)g,
        (__attribute__((address_space(3))) uint32_t*)l, 16, 0, 0);
}

#define WAITVM(n)  asm volatile("s_waitcnt vmcnt(" #n ")" ::: "memory")
#define WAITLGKM0  asm volatile("s_waitcnt lgkmcnt(0)" ::: "memory")

__device__ __forceinline__ void blockbar() {
    __builtin_amdgcn_sched_barrier(0);
    __builtin_amdgcn_s_barrier();
    __builtin_amdgcn_sched_barrier(0);
}

// ===================== prepass (R2-proven): fp32 -> bf16, grid-stride =======
__global__ __launch_bounds__(256)
void cvt_prepass2(const float4* __restrict__ words, const float4* __restrict__ sents,
                  const float4* __restrict__ W,
                  uint4* __restrict__ wordsB, uint4* __restrict__ sentsB,
                  uint4* __restrict__ WB, uint32_t* __restrict__ zp)
{
    constexpr size_t NW8 = (size_t)kM * kD / 8;       // 4,194,304
    constexpr size_t NS8 = (size_t)kB * kS * kD / 8;  //   261,120
    constexpr size_t NB8 = (size_t)kN * kK / 8;       //   262,144
    constexpr size_t NT8 = NW8 + NS8 + NB8;
    if (blockIdx.x == 0) {                            // zero page for invalid rows
        for (int t = threadIdx.x; t < 768; t += 256) zp[t] = 0u;
    }
    const size_t stride = (size_t)gridDim.x * blockDim.x;
    for (size_t i = (size_t)blockIdx.x * blockDim.x + threadIdx.x; i < NT8; i += stride) {
        const float4* src; uint4* dst; size_t j;
        if (i < NW8)            { src = words; dst = wordsB; j = i; }
        else if (i < NW8 + NS8) { src = sents; dst = sentsB; j = i - NW8; }
        else                    { src = W;     dst = WB;     j = i - NW8 - NS8; }
        float4 a  = src[2 * j];
        float4 b2 = src[2 * j + 1];
        uint4 o;
        o.x = pk_bf16x2(a.x,  a.y);
        o.y = pk_bf16x2(a.z,  a.w);
        o.z = pk_bf16x2(b2.x, b2.y);
        o.w = pk_bf16x2(b2.z, b2.w);
        dst[j] = o;
    }
}

// ===================== GEMM v5: v2 staging + 1-barrier rotated schedule =====
// C[m,n] = relu( sum_k A[m,k]*W[n,k] + bias[n] )
// EXACT v2 data path (all-bf16 DMA staging for A and B) — single variable
// changed vs v2: 3 barriers/K-step -> 1 barrier/K-step (rotated prefetch),
// 4 LDS buffers (128 KiB). Lifetime proof:
//  - one WAITLGKM0 per kstep, before the mid barrier => every wave has ZERO
//    outstanding ds_reads at every barrier.
//  - buf[(t+3)&3] (holding tile t-1) is overwritten in phase B of kstep t;
//    its last reads (ag(t-1), phase A of kstep t-1) were drained at kstep
//    t-1's WAITLGKM0, one full barrier earlier.
//  - WAITVM(4) at kstep-t mid leaves exactly tile-(t+2)'s 4 DMAs in flight
//    => tile t+1 (read in phase B) is complete; barrier publishes all waves'
//    slices. Drain to 0 only at t>=62.
__global__ __launch_bounds__(512, 2)
void wsib_gemm_v5(const uint8_t* __restrict__ wordsB,   // [32768][1024] bf16
                  const uint8_t* __restrict__ sentsB,   // [8*255][1024] bf16
                  const uint8_t* __restrict__ WB,       // [1024][2048]  bf16
                  const float*   __restrict__ bias,
                  const int*     __restrict__ smap,
                  const uint8_t* __restrict__ zp,
                  float* __restrict__ out)
{
    __shared__ uint8_t lds[4][2][16384];   // [buf][A=0/B=1][256 rows][64 B]

    const int tid  = threadIdx.x;
    const int w    = tid >> 6;           // wave 0..7
    const int lane = tid & 63;
    const int nT = blockIdx.x;           // 0..3
    const int mT = blockIdx.y;           // 0..127

    const int wm = (w >> 2) * 128;
    const int wn = (w & 3) * 64;
    const int fr = lane & 15, quad = lane >> 4;

    float bv[4];
    #pragma unroll
    for (int ni = 0; ni < 4; ++ni) bv[ni] = bias[nT * 256 + wn + ni * 16 + fr];

    // ---- staging sources: rows w*32+(lane>>2) and +16, 16-B chunk lane&3 ----
    const int lrow = lane >> 2;
    const int ch   = (lane & 3) * 16;
    const int rloc0 = w * 32 + lrow, rloc1 = rloc0 + 16;
    const int gA0 = mT * 256 + rloc0, gA1 = mT * 256 + rloc1;
    const int bIdx = gA0 >> 12;               // tile never crosses batch
    const uint8_t* aw0 = wordsB + (size_t)gA0 * 2048 + ch;
    const uint8_t* aw1 = wordsB + (size_t)gA1 * 2048 + ch;
    const int s0 = smap[gA0], s1 = smap[gA1];
    const uint8_t* as0 = (s0 >= 0) ? sentsB + (size_t)(bIdx * kS + s0) * 2048 + ch : zp + ch;
    const uint8_t* as1 = (s1 >= 0) ? sentsB + (size_t)(bIdx * kS + s1) * 2048 + ch : zp + ch;
    const uint8_t* pB0 = WB + (size_t)(nT * 256 + rloc0) * 4096 + ch;
    const uint8_t* pB1 = WB + (size_t)(nT * 256 + rloc1) * 4096 + ch;

    auto stage = [&](int buf, int t) {
        uint8_t* A  = (uint8_t*)lds[buf][0];
        uint8_t* Bb = (uint8_t*)lds[buf][1];
        const uint8_t* a0 = (t < 32) ? aw0 + t * 64 : as0 + (t - 32) * 64;
        const uint8_t* a1 = (t < 32) ? aw1 + t * 64 : as1 + (t - 32) * 64;
        async16(a0, A + w * 2048);
        async16(a1, A + w * 2048 + 1024);
        async16(pB0 + t * 64, Bb + w * 2048);
        async16(pB1 + t * 64, Bb + w * 2048 + 1024);
    };

    // ---- fragment read offsets (linear layout — bank-minimal for b128) ----
    const int offA = (wm + fr) * 64 + quad * 16;   // + mi*1024
    const int offB = (wn + fr) * 64 + quad * 16;   // + ni*1024

    f32x4 acc[8][4];
    #pragma unroll
    for (int i = 0; i < 8; ++i)
        #pragma unroll
        for (int j = 0; j < 4; ++j) acc[i][j] = (f32x4){0.f, 0.f, 0.f, 0.f};

    // ---- prologue: stage tiles 0,1,2; tile 0 complete; prime frags(0) ----
    stage(0, 0);
    stage(1, 1);
    stage(2, 2);
    WAITVM(8);
    blockbar();

    bf16x8 af[4], bfA[4], bfB[4];
    #pragma unroll
    for (int mi = 0; mi < 4; ++mi)
        af[mi] = *(const bf16x8*)((uint8_t*)lds[0][0] + offA + mi * 1024);
    #pragma unroll
    for (int ni = 0; ni < 4; ++ni)
        bfA[ni] = *(const bf16x8*)((uint8_t*)lds[0][1] + offB + ni * 1024);

    // ---- main loop: 64 K-steps of 32, 1 barrier each ----
    auto kstep = [&](int t, bf16x8 (&bfc)[4], bf16x8 (&bfn)[4]) {
        uint8_t* bufT = (uint8_t*)lds[t & 3][0];

        // phase A: read ag(t) (rows wm+64..127), MFMA-A (acc rows 0..63)
        bf16x8 ag[4];
        #pragma unroll
        for (int mi = 0; mi < 4; ++mi)
            ag[mi] = *(const bf16x8*)(bufT + offA + (mi + 4) * 1024);
        __builtin_amdgcn_s_setprio(1);
        #pragma unroll
        for (int mi = 0; mi < 4; ++mi)
            #pragma unroll
            for (int ni = 0; ni < 4; ++ni)
                acc[mi][ni] = __builtin_amdgcn_mfma_f32_16x16x32_bf16(
                    af[mi], bfc[ni], acc[mi][ni], 0, 0, 0);
        __builtin_amdgcn_s_setprio(0);

        // mid: drain own ds_reads; tile t+1 DMA-complete; publish via barrier
        WAITLGKM0;
        if (t < 62) { WAITVM(4); } else { WAITVM(0); }
        blockbar();

        // phase B: issue DMA for tile t+3, read frags(t+1), MFMA-B
        if (t + 3 < 64) stage((t + 3) & 3, t + 3);
        if (t + 1 < 64) {
            uint8_t* bufNA = (uint8_t*)lds[(t + 1) & 3][0];
            uint8_t* bufNB = (uint8_t*)lds[(t + 1) & 3][1];
            #pragma unroll
            for (int ni = 0; ni < 4; ++ni)
                bfn[ni] = *(const bf16x8*)(bufNB + offB + ni * 1024);
            #pragma unroll
            for (int mi = 0; mi < 4; ++mi)
                af[mi] = *(const bf16x8*)(bufNA + offA + mi * 1024);
        }
        __builtin_amdgcn_s_setprio(1);
        #pragma unroll
        for (int mi = 0; mi < 4; ++mi)
            #pragma unroll
            for (int ni = 0; ni < 4; ++ni)
                acc[mi + 4][ni] = __builtin_amdgcn_mfma_f32_16x16x32_bf16(
                    ag[mi], bfc[ni], acc[mi + 4][ni], 0, 0, 0);
        __builtin_amdgcn_s_setprio(0);
    };

    #pragma unroll 1
    for (int t2 = 0; t2 < 32; ++t2) {
        kstep(2 * t2,     bfA, bfB);
        kstep(2 * t2 + 1, bfB, bfA);
    }

    // ---- epilogue: bias + relu, fp32 store ----
    // C/D layout (verified): col = lane&15, row = quad*4 + r
    const int rowBase = mT * 256 + wm + quad * 4;
    const int colBase = nT * 256 + wn + fr;
    #pragma unroll
    for (int mi = 0; mi < 8; ++mi) {
        #pragma unroll
        for (int ni = 0; ni < 4; ++ni) {
            const int col = colBase + ni * 16;
            #pragma unroll
            for (int r = 0; r < 4; ++r) {
                const int row = rowBase + mi * 16 + r;
                out[(size_t)row * kN + col] = fmaxf(acc[mi][ni][r] + bv[ni], 0.f);
            }
        }
    }
}

// ===================== fallback (R2 kernel, no-workspace path) ==============
#define TILE_M 128
#define TILE_N 128
#define TILE_K 32
#define LDS_STRIDE 20
__global__ __launch_bounds__(256)
void wsib_gemm_fb(const float* __restrict__ words, const float* __restrict__ sents,
                  const float* __restrict__ W, const float* __restrict__ bias,
                  const int* __restrict__ smap, float* __restrict__ out)
{
    __shared__ uint32_t Asm[TILE_M * LDS_STRIDE];
    __shared__ uint32_t Bsm[TILE_N * LDS_STRIDE];
    const int tid = threadIdx.x, nT = blockIdx.x, mT = blockIdx.y;
    const int sRow = tid >> 1, half = tid & 1;
    const int mRow = mT * TILE_M + sRow, bIdx = mRow >> 12;
    const float* wsrc = words + (size_t)mRow * kD + half * 16;
    const int sidx = smap[mRow];
    const float* ssrc = (sidx >= 0) ? sents + ((size_t)bIdx * kS + sidx) * kD + half * 16 : nullptr;
    const float* bsrc = W + (size_t)(nT * TILE_N + sRow) * kK + half * 16;
    uint32_t* adst = &Asm[sRow * LDS_STRIDE + half * 8];
    uint32_t* bdst = &Bsm[sRow * LDS_STRIDE + half * 8];
    const int lane = tid & 63, wv = tid >> 6;
    const int wm = (wv & 1) * 64, wn = (wv >> 1) * 64;
    const int fr = lane & 15, quad = lane >> 4;
    f32x4 acc[4][4];
    #pragma unroll
    for (int i = 0; i < 4; ++i)
        #pragma unroll
        for (int j = 0; j < 4; ++j) acc[i][j] = (f32x4){0.f, 0.f, 0.f, 0.f};
    float4 ra[4], rb[4];
    {
        const float4* pa = (const float4*)wsrc; const float4* pb = (const float4*)bsrc;
        #pragma unroll
        for (int i = 0; i < 4; ++i) { ra[i] = pa[i]; rb[i] = pb[i]; }
    }
    for (int k0 = 0; k0 < kK; k0 += TILE_K) {
        uint32_t pa[8], pb[8];
        #pragma unroll
        for (int i = 0; i < 4; ++i) {
            pa[2*i] = pk_bf16x2(ra[i].x, ra[i].y); pa[2*i+1] = pk_bf16x2(ra[i].z, ra[i].w);
            pb[2*i] = pk_bf16x2(rb[i].x, rb[i].y); pb[2*i+1] = pk_bf16x2(rb[i].z, rb[i].w);
        }
        __syncthreads();
        ((uint4*)adst)[0] = make_uint4(pa[0], pa[1], pa[2], pa[3]);
        ((uint4*)adst)[1] = make_uint4(pa[4], pa[5], pa[6], pa[7]);
        ((uint4*)bdst)[0] = make_uint4(pb[0], pb[1], pb[2], pb[3]);
        ((uint4*)bdst)[1] = make_uint4(pb[4], pb[5], pb[6], pb[7]);
        __syncthreads();
        const int k1 = k0 + TILE_K;
        if (k1 < kK) {
            const float* asrc = (k1 < kD) ? (wsrc + k1) : (ssrc ? (ssrc + (k1 - kD)) : nullptr);
            if (asrc) { const float4* p = (const float4*)asrc;
                #pragma unroll
                for (int i = 0; i < 4; ++i) ra[i] = p[i];
            } else {
                #pragma unroll
                for (int i = 0; i < 4; ++i) ra[i] = make_float4(0.f, 0.f, 0.f, 0.f);
            }
            const float4* p = (const float4*)(bsrc + k1);
            #pragma unroll
            for (int i = 0; i < 4; ++i) rb[i] = p[i];
        }
        bf16x8 af[4], bfv[4];
        #pragma unroll
        for (int mi = 0; mi < 4; ++mi)
            af[mi] = *(const bf16x8*)&Asm[(wm + mi * 16 + fr) * LDS_STRIDE + quad * 4];
        #pragma unroll
        for (int ni = 0; ni < 4; ++ni)
            bfv[ni] = *(const bf16x8*)&Bsm[(wn + ni * 16 + fr) * LDS_STRIDE + quad * 4];
        #pragma unroll
        for (int mi = 0; mi < 4; ++mi)
            #pragma unroll
            for (int ni = 0; ni < 4; ++ni)
                acc[mi][ni] = __builtin_amdgcn_mfma_f32_16x16x32_bf16(af[mi], bfv[ni], acc[mi][ni], 0, 0, 0);
    }
    const int rowBase = mT * TILE_M + wm, colBase = nT * TILE_N + wn;
    float bv[4];
    #pragma unroll
    for (int ni = 0; ni < 4; ++ni) bv[ni] = bias[colBase + ni * 16 + fr];
    #pragma unroll
    for (int mi = 0; mi < 4; ++mi)
        #pragma unroll
        for (int ni = 0; ni < 4; ++ni) {
            const int col = colBase + ni * 16 + fr;
            #pragma unroll
            for (int r = 0; r < 4; ++r) {
                const int row = rowBase + mi * 16 + quad * 4 + r;
                out[(size_t)row * kN + col] = fmaxf(acc[mi][ni][r] + bv[ni], 0.f);
            }
        }
}

extern "C" void kernel_launch(void* const* d_in, const int* in_sizes, int n_in,
                              void* d_out, int out_size, void* d_ws, size_t ws_size,
                              hipStream_t stream) {
    const float* words = (const float*)d_in[0];   // [8, 4096, 1024] f32
    const float* sents = (const float*)d_in[1];   // [8, 255, 1024]  f32
    const float* W     = (const float*)d_in[2];   // [1024, 2048]    f32
    const float* bias  = (const float*)d_in[3];   // [1024]          f32
    const int*   smap  = (const int*)d_in[4];     // [8, 4096]       i32
    float* out = (float*)d_out;                   // [8, 4096, 1024] f32

    if (ws_size >= WS_NEED) {
        uint8_t* ws = (uint8_t*)d_ws;
        uint4* wordsB = (uint4*)(ws + WS_WORDS);
        uint4* sentsB = (uint4*)(ws + WS_SENTS);
        uint4* WB     = (uint4*)(ws + WS_W);
        uint32_t* zp  = (uint32_t*)(ws + WS_ZP);
        cvt_prepass2<<<2048, 256, 0, stream>>>(
            (const float4*)words, (const float4*)sents, (const float4*)W,
            wordsB, sentsB, WB, zp);
        dim3 grid(kN / 256, kM / 256);            // (4, 128)
        wsib_gemm_v5<<<grid, 512, 0, stream>>>(
            (const uint8_t*)wordsB, (const uint8_t*)sentsB, (const uint8_t*)WB,
            bias, smap, (const uint8_t*)zp, out);
    } else {
        dim3 grid(kN / TILE_N, kM / TILE_M);
        wsib_gemm_fb<<<grid, 256, 0, stream>>>(words, sents, W, bias, smap, out);
    }
}